// Round 8
// baseline (220.947 us; speedup 1.0000x reference)
//
#include <hip/hip_runtime.h>
#include <hip/hip_bf16.h>
#include <hip/hip_fp16.h>
#include <math.h>

// GAT forward. k0: pack {src,dst} -> uint32; k1 heterogeneous fused:
// zero-staging fp16-MFMA projection (blocks 0..nG-1) + partitioned
// slotted-CSR scatter over the packed edge stream (blocks nG..);
// k5: single-pass wave-per-node aggregate, deferred normalization, int8 feat.
// R21 (this round): BATCHED scatter atomics. R18/R20 nulls + WRITE_SIZE
//      anatomy (51MB = 1.6M x 32B fabric write-through) + rate arithmetic
//      (measured 7.3 atomics/cy == ~6K waves x 1 outstanding / ~700cy fabric
//      latency) prove the scatter is atomic-LATENCY-bound at depth 1: the
//      pos-dependent slots store forces vmcnt(0) before the next atomic.
//      Fix: issue all 4 predicated atomicAdds back-to-back, sched_barrier(0),
//      then the 4 dependent stores -> 4x outstanding per wave.
// R19: per-(node,head)-scaled INT8 feat (absmax 1.95e-3 vs 6.5e-3 budget) —
//      time-NULL -> k5 request-count-bound (~2 random lines/edge floor).
// R20: packed stream: FETCH 62.7->38.1MB confirmed, time null -> not
//      stream-BW-bound.
// R6: few-cursor binning = atomic serialization disaster.
// R8: heterogeneous fusion shares worst-case LDS across all blocks.
// R9: latency-bound scatter needs >=8 blocks/CU.
// R11: unroll-8 / 8-edge chunks regress — not MLP-limited.
// R12: __shfl from divergently-exited lanes = UB; broadcast loads only.
// R13: GEMM-first ordering lets scatter set k1's end time alone.
// R14/R15 (FAILED): head-sliced 4-pass k5 — 200K-wave fixed overhead.
// R17 (NULL): XCD-aligned k5 mapping — k5 not read-latency-bound.
// R18 (NULL): workgroup-scope atomics — same codegen/traffic.

#define NEG_SLOPE 0.2f
#define HEADS 4
#define FEAT_OUT 32
#define FEAT_ALL 128
#define IN_FEAT 128
#define CAP 96       // slots per node; deg~Poisson(32), P(>96) ~ 1e-18
#define KP 136       // LDS K-stride in halves (sf tile only)
#define NB_SC 2048   // scatter blocks (256 per XCD partition)

typedef _Float16 half8 __attribute__((ext_vector_type(8)));
typedef float float4v __attribute__((ext_vector_type(4)));
typedef unsigned int uint4v __attribute__((ext_vector_type(4)));

__device__ __forceinline__ float leaky(float v) {
    return v > 0.f ? v : NEG_SLOPE * v;
}

// ---- K0: pack src/dst (both < 65536) into one uint32 per edge ----
__global__ __launch_bounds__(256) void k0_pack(
    const int* __restrict__ src, const int* __restrict__ dst,
    unsigned int* __restrict__ ds, int E4) {
    const int i0 = (blockIdx.x * 256 + threadIdx.x) * 4;
    if (i0 >= E4) return;
    uint4v s4 = *(const uint4v*)(src + i0);
    uint4v d4 = *(const uint4v*)(dst + i0);
    uint4v r;
#pragma unroll
    for (int j = 0; j < 4; j++) r[j] = (s4[j] << 16) | d4[j];
    *(uint4v*)(ds + i0) = r;
}

// ---- K1 fused: blocks [0,nG) MFMA GEMM; blocks [nG, nG+NB_SC) scatter ----
__global__ __launch_bounds__(256) void k1_fused(
    const unsigned int* __restrict__ ds,
    const int* __restrict__ src, const int* __restrict__ dst, int E,
    int* __restrict__ cnt, unsigned short* __restrict__ slots,
    const float* __restrict__ h, const float* __restrict__ W,
    const float* __restrict__ attn_l, const float* __restrict__ attn_r,
    unsigned char* __restrict__ feat8, float2* __restrict__ elsc,
    float* __restrict__ er, int N, int nG) {
    __shared__ _Float16 sf[64 * KP];    // 17.4 KB (GEMM epilogue only)
    const int t = threadIdx.x;

    if ((int)blockIdx.x >= nG) {
        // ---------- scatter: partition p -> XCD p (round-robin dispatch) ----------
        const int b = blockIdx.x - nG;
        const int p = b & 7;
        const int g = b >> 3;                    // 0..255
        const int NPER = (N + 7) >> 3;
        const int lo = p * NPER;
        const int hi = (lo + NPER < N) ? lo + NPER : N;
        const int tpp = (NB_SC >> 3) * 256;      // threads per partition
        const int E4 = E & ~3;
        for (int e0 = (g * 256 + t) * 4; e0 < E4; e0 += tpp * 4) {
            uint4v q = *(const uint4v*)(ds + e0);   // 4 packed edges, one load
            int d[4], pos[4];
            bool v[4];
#pragma unroll
            for (int j = 0; j < 4; j++) {
                d[j] = (int)(q[j] & 0xffffu);
                v[j] = (d[j] >= lo && d[j] < hi);
            }
            // phase 1: issue all 4 atomics back-to-back (independent -> no
            // waitcnt between issues; 4 outstanding fabric RMWs per wave)
#pragma unroll
            for (int j = 0; j < 4; j++)
                if (v[j]) pos[j] = atomicAdd(&cnt[d[j]], 1);
            // fence: stop the compiler sinking atomics into the store branches
            __builtin_amdgcn_sched_barrier(0);
            // phase 2: dependent stores (compiler waits vmcnt per-use)
#pragma unroll
            for (int j = 0; j < 4; j++)
                if (v[j] && pos[j] < CAP)
                    slots[(size_t)d[j] * CAP + pos[j]] = (unsigned short)(q[j] >> 16);
        }
        // tail (E not multiple of 4): each partition's group g==0 handles it
        if (g == 0 && t < E - E4) {
            int e = E4 + t;
            int d = dst[e];
            if (d >= lo && d < hi) {
                int pos = atomicAdd(&cnt[d], 1);
                if (pos < CAP) slots[(size_t)d * CAP + pos] = (unsigned short)src[e];
            }
        }
        return;
    }

    // ---------- GEMM: feat = h@W + epilogue, operands streamed ----------
    const int n0 = blockIdx.x * 64;
    const int wv_ = t >> 6;
    const int lane = t & 63;
    const int m16 = lane & 15;
    const int quad = lane >> 4;
    const int rowA = wv_ * 16 + m16;
    int nA = n0 + rowA; if (nA > N - 1) nA = N - 1;   // clamp: pad rows never stored
    const float* hp = h + (size_t)nA * IN_FEAT + quad * 8;

    float4v acc[8];
#pragma unroll
    for (int i = 0; i < 8; i++) acc[i] = (float4v){0.f, 0.f, 0.f, 0.f};

#pragma unroll
    for (int k0 = 0; k0 < 128; k0 += 32) {
        float4 a0 = *(const float4*)(hp + k0);
        float4 a1 = *(const float4*)(hp + k0 + 4);
        half8 a;
        a[0] = (_Float16)a0.x; a[1] = (_Float16)a0.y;
        a[2] = (_Float16)a0.z; a[3] = (_Float16)a0.w;
        a[4] = (_Float16)a1.x; a[5] = (_Float16)a1.y;
        a[6] = (_Float16)a1.z; a[7] = (_Float16)a1.w;
        const float* wp = W + (size_t)(k0 + quad * 8) * FEAT_ALL + m16;
#pragma unroll
        for (int tN = 0; tN < 8; tN++) {
            const float* wpt = wp + tN * 16;
            half8 b;
            b[0] = (_Float16)wpt[0];
            b[1] = (_Float16)wpt[FEAT_ALL];
            b[2] = (_Float16)wpt[2 * FEAT_ALL];
            b[3] = (_Float16)wpt[3 * FEAT_ALL];
            b[4] = (_Float16)wpt[4 * FEAT_ALL];
            b[5] = (_Float16)wpt[5 * FEAT_ALL];
            b[6] = (_Float16)wpt[6 * FEAT_ALL];
            b[7] = (_Float16)wpt[7 * FEAT_ALL];
            acc[tN] = __builtin_amdgcn_mfma_f32_16x16x32_f16(a, b, acc[tN], 0, 0, 0);
        }
    }

#pragma unroll
    for (int tN = 0; tN < 8; tN++)
#pragma unroll
        for (int r = 0; r < 4; r++) {
            int row = wv_ * 16 + quad * 4 + r;   // C/D: col=lane&15, row=quad*4+reg
            sf[row * KP + tN * 16 + m16] = (_Float16)acc[tN][r];
        }
    __syncthreads();

    // fused epilogue: thread (r,hh) computes el/er/scale over its 32 feats,
    // then packs the same 32 feats to scaled int8. No extra sync needed.
    {
        int r = t >> 2, hh = t & 3;
        int n = n0 + r;
        if (n < N) {
            const _Float16* sp_ = &sf[r * KP + hh * FEAT_OUT];
            float sl = 0.f, sr = 0.f, mx = 0.f;
#pragma unroll
            for (int f = 0; f < FEAT_OUT; f++) {
                float v = (float)sp_[f];
                sl += v * attn_l[hh * FEAT_OUT + f];
                sr += v * attn_r[hh * FEAT_OUT + f];
                mx = fmaxf(mx, fabsf(v));
            }
            er[n * HEADS + hh] = sr;
            elsc[n * HEADS + hh] = make_float2(sl, mx * (1.f / 127.f));
            const float inv = mx > 0.f ? 127.f / mx : 0.f;
            unsigned int w[8];
#pragma unroll
            for (int k2 = 0; k2 < 8; k2++) {
                unsigned int wv = 0;
#pragma unroll
                for (int j = 0; j < 4; j++) {
                    float v = (float)sp_[k2 * 4 + j];
                    int q = __float2int_rn(v * inv);
                    wv |= ((unsigned int)(q & 0xff)) << (8 * j);
                }
                w[k2] = wv;
            }
            uint4* dp = (uint4*)(feat8 + (size_t)n * FEAT_ALL + hh * 32);
            dp[0] = make_uint4(w[0], w[1], w[2], w[3]);
            dp[1] = make_uint4(w[4], w[5], w[6], w[7]);
        }
    }
}

// ---- K5: wave-per-node single-pass aggregate, deferred normalization ----
// 4 edges/iter; lane -> (edge sub4=lane>>4, q4=lane&15 -> feats 8q4..8q4+7,
// head hh=q4>>2). Per edge: 8B int8 feat + 8B {el,scale}. Scale folded in ex.
__global__ __launch_bounds__(256) void k5_node(
    const int* __restrict__ cnt, const unsigned short* __restrict__ slots,
    const float2* __restrict__ elsc, const float* __restrict__ er,
    const unsigned char* __restrict__ feat8, const float* __restrict__ bias,
    float* __restrict__ out, int N) {
    const int lane = threadIdx.x & 63;
    const int p = blockIdx.x & 7;
    const int g = blockIdx.x >> 3;
    const int NPER = (N + 7) >> 3;
    const int hi = ((p + 1) * NPER < N) ? (p + 1) * NPER : N;
    const int n = p * NPER + g * 4 + (threadIdx.x >> 6);
    if (n >= hi) return;                 // wave-uniform exit
    int deg = cnt[n];
    if (deg > CAP) deg = CAP;

    const int sub4 = lane >> 4;     // edge within group of 4
    const int q4 = lane & 15;       // feats 8q4 .. 8q4+7
    const int hh = q4 >> 2;         // head of those feats
    const float ernh = er[n * HEADS + hh];

    float acc[8];
#pragma unroll
    for (int j = 0; j < 8; j++) acc[j] = 0.f;
    float den = 0.f;

    const unsigned short* sp = slots + (size_t)n * CAP;
#pragma unroll 4
    for (int i = sub4; i < deg; i += 4) {
        int s = (int)sp[i];                       // 16-lane broadcast load
        float2 es = elsc[s * HEADS + hh];         // {el, scale/127}
        float ex = __expf(leaky(es.x + ernh));
        uint2 u = *(const uint2*)(feat8 + (size_t)s * FEAT_ALL + q4 * 8);
        float exs = ex * es.y;
        den += ex;
        union { uint2 v; signed char b[8]; } cv;
        cv.v = u;
        acc[0] += exs * (float)cv.b[0];
        acc[1] += exs * (float)cv.b[1];
        acc[2] += exs * (float)cv.b[2];
        acc[3] += exs * (float)cv.b[3];
        acc[4] += exs * (float)cv.b[4];
        acc[5] += exs * (float)cv.b[5];
        acc[6] += exs * (float)cv.b[6];
        acc[7] += exs * (float)cv.b[7];
    }

    // joint reduction over the 4 edge-subgroups
#pragma unroll
    for (int j = 0; j < 8; j++) {
        acc[j] += __shfl_xor(acc[j], 16);
        acc[j] += __shfl_xor(acc[j], 32);
    }
    den += __shfl_xor(den, 16);
    den += __shfl_xor(den, 32);
    const float idh = 1.f / fmaxf(den, 1e-9f);

    // bias + relu (per head), then mean over heads (lanes q4, q4^4, q4^8, q4^12)
    const float4 b0 = ((const float4*)bias)[q4 * 2];
    const float4 b1 = ((const float4*)bias)[q4 * 2 + 1];
    float v[8];
    v[0] = fmaxf(acc[0] * idh + b0.x, 0.f); v[1] = fmaxf(acc[1] * idh + b0.y, 0.f);
    v[2] = fmaxf(acc[2] * idh + b0.z, 0.f); v[3] = fmaxf(acc[3] * idh + b0.w, 0.f);
    v[4] = fmaxf(acc[4] * idh + b1.x, 0.f); v[5] = fmaxf(acc[5] * idh + b1.y, 0.f);
    v[6] = fmaxf(acc[6] * idh + b1.z, 0.f); v[7] = fmaxf(acc[7] * idh + b1.w, 0.f);
#pragma unroll
    for (int j = 0; j < 8; j++) {
        v[j] += __shfl_xor(v[j], 4);
        v[j] += __shfl_xor(v[j], 8);
    }
    if (lane < 4) {
        float4 o0 = make_float4(v[0] * 0.25f, v[1] * 0.25f, v[2] * 0.25f, v[3] * 0.25f);
        float4 o1 = make_float4(v[4] * 0.25f, v[5] * 0.25f, v[6] * 0.25f, v[7] * 0.25f);
        float* op = out + (size_t)n * FEAT_OUT + lane * 8;
        ((float4*)op)[0] = o0;
        ((float4*)op)[1] = o1;
    }
}

extern "C" void kernel_launch(void* const* d_in, const int* in_sizes, int n_in,
                              void* d_out, int out_size, void* d_ws, size_t ws_size,
                              hipStream_t stream) {
    const float* h      = (const float*)d_in[0];
    const float* W      = (const float*)d_in[1];
    const float* attn_l = (const float*)d_in[2];
    const float* attn_r = (const float*)d_in[3];
    const float* bias   = (const float*)d_in[4];
    const int*   src    = (const int*)d_in[5];
    const int*   dst    = (const int*)d_in[6];
    float* out = (float*)d_out;

    const int N = in_sizes[0] / IN_FEAT;
    const int E = in_sizes[5];

    // workspace layout
    unsigned char* feat8 = (unsigned char*)d_ws;           // N*128 int8 (6.4 MB)
    float2* elsc = (float2*)(feat8 + (size_t)N * FEAT_ALL);// N*4 {el, scale} (1.6 MB)
    float* er  = (float*)(elsc + (size_t)N * HEADS);       // N*4 (0.8 MB)
    int* cnt   = (int*)(er + (size_t)N * HEADS);           // N
    unsigned short* slots = (unsigned short*)(cnt + N);    // N*CAP (9.6 MB)
    unsigned int* ds = (unsigned int*)(slots + (size_t)N * CAP); // E (6.4 MB)

    hipMemsetAsync(cnt, 0, (size_t)N * sizeof(int), stream);

    const int E4 = E & ~3;
    k0_pack<<<(E4 / 4 + 255) / 256, 256, 0, stream>>>(src, dst, ds, E4);

    const int nG = (N + 63) / 64;
    k1_fused<<<nG + NB_SC, 256, 0, stream>>>(ds, src, dst, E, cnt, slots,
                                             h, W, attn_l, attn_r,
                                             feat8, elsc, er, N, nG);

    const int NPER = (N + 7) >> 3;
    const int nb5 = 8 * ((NPER + 3) / 4);
    k5_node<<<nb5, 256, 0, stream>>>(cnt, slots, elsc, er, feat8, bias, out, N);
}

// Round 9
// 183.055 us; speedup vs baseline: 1.2070x; 1.2070x over previous
//
#include <hip/hip_runtime.h>
#include <hip/hip_bf16.h>
#include <hip/hip_fp16.h>
#include <math.h>

// GAT forward — atomic-free CSR build.
// R22 (this round): scatter's 1.6M device-scope atomicAdds hit a hard fabric
//      rate (7.4/cy; R18 scope null, R20 byte-diet null, R21 depth-4 null)
//      -> REMOVE them. 2-level counting sort: L1 = GEMM (unchanged) + 512
//      pack/hist blocks (LDS hist of dst>>7); s1/s2 tiny scans; p2 places
//      edges into bucket-contiguous srt[] via LDS cursors (plain stores);
//      p3 per-bucket (128 nodes) exact CSR: rpd[n]=(rowptr<<8)|deg +
//      slots16 u16 src list. Zero global atomics, no CAP, no memset.
// R19: per-(node,head)-scaled INT8 feat (absmax 1.95e-3 vs 6.5e-3) kept.
// k5: identical inner loop, reads rpd + contiguous slots16 segment.
// History: R6 few-cursor binning disaster; R9 scatter needs many blocks;
// R12 no shfl from exited lanes; R13 GEMM-first; R14/R15 head-split failed
// (per-wave fixed overhead x4); R17 XCD-align null; R18/R20/R21 atomic nulls.

#define NEG_SLOPE 0.2f
#define HEADS 4
#define FEAT_OUT 32
#define FEAT_ALL 128
#define IN_FEAT 128
#define KP 136        // LDS K-stride in halves (sf tile only)
#define NBLK1 512     // pack/hist + place blocks
#define NBKT_MAX 512  // max buckets (N<=65536 -> <=512)

typedef _Float16 half8 __attribute__((ext_vector_type(8)));
typedef float float4v __attribute__((ext_vector_type(4)));
typedef unsigned int uint4v __attribute__((ext_vector_type(4)));

__device__ __forceinline__ float leaky(float v) {
    return v > 0.f ? v : NEG_SLOPE * v;
}

// ---- L1 fused: blocks [0,nG) MFMA GEMM; blocks [nG, nG+NBLK1) pack+hist ----
__global__ __launch_bounds__(256) void k1_fused(
    const int* __restrict__ src, const int* __restrict__ dst, int E,
    int che, int nbkt,
    unsigned int* __restrict__ ds, int* __restrict__ hist,
    const float* __restrict__ h, const float* __restrict__ W,
    const float* __restrict__ attn_l, const float* __restrict__ attn_r,
    unsigned char* __restrict__ feat8, float2* __restrict__ elsc,
    float* __restrict__ er, int N, int nG) {
    __shared__ _Float16 sf[64 * KP];    // 17.4 KB; pack blocks reuse as hist
    const int t = threadIdx.x;

    if ((int)blockIdx.x >= nG) {
        // ---------- pack + per-block bucket histogram ----------
        const int blk = blockIdx.x - nG;        // 0..NBLK1-1
        int* hb = (int*)sf;                     // nbkt bins
        for (int i = t; i < nbkt; i += 256) hb[i] = 0;
        __syncthreads();
        const int e_lo = blk * che;
        int e_hi = e_lo + che; if (e_hi > E) e_hi = E;
        for (int e0 = e_lo + t * 4; e0 < e_hi; e0 += 1024) {
            if (e0 + 3 < e_hi) {
                uint4v s4 = *(const uint4v*)(src + e0);
                uint4v d4 = *(const uint4v*)(dst + e0);
                uint4v r;
#pragma unroll
                for (int j = 0; j < 4; j++) r[j] = (s4[j] << 16) | d4[j];
                *(uint4v*)(ds + e0) = r;
#pragma unroll
                for (int j = 0; j < 4; j++) atomicAdd(&hb[d4[j] >> 7], 1);
            } else {
                for (int e = e0; e < e_hi; ++e) {
                    unsigned s = (unsigned)src[e], d = (unsigned)dst[e];
                    ds[e] = (s << 16) | d;
                    atomicAdd(&hb[d >> 7], 1);
                }
            }
        }
        __syncthreads();
        // column-major hist: hist[b*NBLK1 + blk] (coalesced reads in s1)
        for (int i = t; i < nbkt; i += 256) hist[i * NBLK1 + blk] = hb[i];
        return;
    }

    // ---------- GEMM: feat = h@W + epilogue, operands streamed ----------
    const int n0 = blockIdx.x * 64;
    const int wv_ = t >> 6;
    const int lane = t & 63;
    const int m16 = lane & 15;
    const int quad = lane >> 4;
    const int rowA = wv_ * 16 + m16;
    int nA = n0 + rowA; if (nA > N - 1) nA = N - 1;   // clamp: pad rows never stored
    const float* hp = h + (size_t)nA * IN_FEAT + quad * 8;

    float4v acc[8];
#pragma unroll
    for (int i = 0; i < 8; i++) acc[i] = (float4v){0.f, 0.f, 0.f, 0.f};

#pragma unroll
    for (int k0 = 0; k0 < 128; k0 += 32) {
        float4 a0 = *(const float4*)(hp + k0);
        float4 a1 = *(const float4*)(hp + k0 + 4);
        half8 a;
        a[0] = (_Float16)a0.x; a[1] = (_Float16)a0.y;
        a[2] = (_Float16)a0.z; a[3] = (_Float16)a0.w;
        a[4] = (_Float16)a1.x; a[5] = (_Float16)a1.y;
        a[6] = (_Float16)a1.z; a[7] = (_Float16)a1.w;
        const float* wp = W + (size_t)(k0 + quad * 8) * FEAT_ALL + m16;
#pragma unroll
        for (int tN = 0; tN < 8; tN++) {
            const float* wpt = wp + tN * 16;
            half8 b;
            b[0] = (_Float16)wpt[0];
            b[1] = (_Float16)wpt[FEAT_ALL];
            b[2] = (_Float16)wpt[2 * FEAT_ALL];
            b[3] = (_Float16)wpt[3 * FEAT_ALL];
            b[4] = (_Float16)wpt[4 * FEAT_ALL];
            b[5] = (_Float16)wpt[5 * FEAT_ALL];
            b[6] = (_Float16)wpt[6 * FEAT_ALL];
            b[7] = (_Float16)wpt[7 * FEAT_ALL];
            acc[tN] = __builtin_amdgcn_mfma_f32_16x16x32_f16(a, b, acc[tN], 0, 0, 0);
        }
    }

#pragma unroll
    for (int tN = 0; tN < 8; tN++)
#pragma unroll
        for (int r = 0; r < 4; r++) {
            int row = wv_ * 16 + quad * 4 + r;   // C/D: col=lane&15, row=quad*4+reg
            sf[row * KP + tN * 16 + m16] = (_Float16)acc[tN][r];
        }
    __syncthreads();

    // fused epilogue: thread (r,hh) computes el/er/scale over its 32 feats,
    // then packs the same 32 feats to scaled int8.
    {
        int r = t >> 2, hh = t & 3;
        int n = n0 + r;
        if (n < N) {
            const _Float16* sp_ = &sf[r * KP + hh * FEAT_OUT];
            float sl = 0.f, sr = 0.f, mx = 0.f;
#pragma unroll
            for (int f = 0; f < FEAT_OUT; f++) {
                float v = (float)sp_[f];
                sl += v * attn_l[hh * FEAT_OUT + f];
                sr += v * attn_r[hh * FEAT_OUT + f];
                mx = fmaxf(mx, fabsf(v));
            }
            er[n * HEADS + hh] = sr;
            elsc[n * HEADS + hh] = make_float2(sl, mx * (1.f / 127.f));
            const float inv = mx > 0.f ? 127.f / mx : 0.f;
            unsigned int w[8];
#pragma unroll
            for (int k2 = 0; k2 < 8; k2++) {
                unsigned int wv = 0;
#pragma unroll
                for (int j = 0; j < 4; j++) {
                    float v = (float)sp_[k2 * 4 + j];
                    int q = __float2int_rn(v * inv);
                    wv |= ((unsigned int)(q & 0xff)) << (8 * j);
                }
                w[k2] = wv;
            }
            uint4* dp = (uint4*)(feat8 + (size_t)n * FEAT_ALL + hh * 32);
            dp[0] = make_uint4(w[0], w[1], w[2], w[3]);
            dp[1] = make_uint4(w[4], w[5], w[6], w[7]);
        }
    }
}

// ---- s1: per-bucket exclusive prefix over the 512 block histograms ----
__global__ __launch_bounds__(256) void s1_scan(
    const int* __restrict__ hist, int* __restrict__ base1,
    int* __restrict__ tot, int nbkt) {
    __shared__ int sm[256];
    const int b = blockIdx.x;       // bucket
    const int t = threadIdx.x;
    const int v0 = hist[b * NBLK1 + 2 * t];
    const int v1 = hist[b * NBLK1 + 2 * t + 1];
    const int s = v0 + v1;
    sm[t] = s; __syncthreads();
    for (int off = 1; off < 256; off <<= 1) {
        int x = (t >= off) ? sm[t - off] : 0;
        __syncthreads();
        sm[t] += x;
        __syncthreads();
    }
    const int excl = sm[t] - s;
    base1[(2 * t) * nbkt + b] = excl;         // row-major for p2
    base1[(2 * t + 1) * nbkt + b] = excl + v0;
    if (t == 255) tot[b] = sm[255];
}

// ---- s2: exclusive scan over bucket totals -> bucket bases bb[0..nbkt] ----
__global__ __launch_bounds__(256) void s2_scan(
    const int* __restrict__ tot, int* __restrict__ bb, int nbkt) {
    __shared__ int sm[256];
    const int t = threadIdx.x;
    const int v0 = (2 * t < nbkt) ? tot[2 * t] : 0;
    const int v1 = (2 * t + 1 < nbkt) ? tot[2 * t + 1] : 0;
    const int s = v0 + v1;
    sm[t] = s; __syncthreads();
    for (int off = 1; off < 256; off <<= 1) {
        int x = (t >= off) ? sm[t - off] : 0;
        __syncthreads();
        sm[t] += x;
        __syncthreads();
    }
    const int excl = sm[t] - s;
    if (2 * t <= nbkt) bb[2 * t] = excl;
    if (2 * t + 1 <= nbkt) bb[2 * t + 1] = excl + v0;
}

// ---- p2: place edges into bucket-contiguous srt[] (LDS cursors only) ----
__global__ __launch_bounds__(256) void p2_place(
    const unsigned int* __restrict__ ds, const int* __restrict__ base1,
    const int* __restrict__ bb, unsigned int* __restrict__ srt,
    int E, int che, int nbkt) {
    __shared__ int cur[NBKT_MAX];
    const int t = threadIdx.x;
    const int blk = blockIdx.x;
    for (int i = t; i < nbkt; i += 256)
        cur[i] = bb[i] + base1[blk * nbkt + i];
    __syncthreads();
    const int e_lo = blk * che;
    int e_hi = e_lo + che; if (e_hi > E) e_hi = E;
    for (int e0 = e_lo + t * 4; e0 < e_hi; e0 += 1024) {
        if (e0 + 3 < e_hi) {
            uint4v q = *(const uint4v*)(ds + e0);
#pragma unroll
            for (int j = 0; j < 4; j++) {
                int b = (int)(q[j] & 0xffffu) >> 7;
                int idx = atomicAdd(&cur[b], 1);
                srt[idx] = q[j];
            }
        } else {
            for (int e = e0; e < e_hi; ++e) {
                unsigned q = ds[e];
                int b = (int)(q & 0xffffu) >> 7;
                int idx = atomicAdd(&cur[b], 1);
                srt[idx] = q;
            }
        }
    }
}

// ---- p3: per-bucket exact CSR: rpd[n]=(rowptr<<8)|deg, slots16 src list ----
__global__ __launch_bounds__(256) void p3_bucket(
    const unsigned int* __restrict__ srt, const int* __restrict__ bb,
    unsigned short* __restrict__ slots16, unsigned int* __restrict__ rpd,
    int N) {
    __shared__ int h2[128];
    __shared__ int nbuf[128];
    const int b = blockIdx.x;
    const int t = threadIdx.x;
    const int s0 = bb[b];
    const int M = bb[b + 1] - s0;
    const int lo = b << 7;
    if (t < 128) h2[t] = 0;
    __syncthreads();
    for (int i = t; i < M; i += 256) {
        unsigned q = srt[s0 + i];
        atomicAdd(&h2[(int)(q & 0xffffu) - lo], 1);
    }
    __syncthreads();
    int hv = 0;
    if (t < 128) hv = h2[t];
    for (int off = 1; off < 128; off <<= 1) {
        int x = 0;
        if (t < 128 && t >= off) x = h2[t - off];
        __syncthreads();
        if (t < 128) h2[t] += x;
        __syncthreads();
    }
    if (t < 128) {
        const int excl = h2[t] - hv;
        nbuf[t] = excl;
        const int n = lo + t;
        if (n < N) {
            int dg = hv > 255 ? 255 : hv;
            rpd[n] = ((unsigned)(s0 + excl) << 8) | (unsigned)dg;
        }
    }
    __syncthreads();
    if (t < 128) h2[t] = nbuf[t];       // reset cursors to exclusive bases
    __syncthreads();
    for (int i = t; i < M; i += 256) {
        unsigned q = srt[s0 + i];
        int n7 = (int)(q & 0xffffu) - lo;
        int r = atomicAdd(&h2[n7], 1);
        slots16[s0 + r] = (unsigned short)(q >> 16);
    }
}

// ---- K5: wave-per-node single-pass aggregate, deferred normalization ----
// 4 edges/iter; lane -> (edge sub4=lane>>4, q4=lane&15 -> feats 8q4..8q4+7,
// head hh=q4>>2). Per edge: 8B int8 feat + 8B {el,scale}. Scale folded in ex.
__global__ __launch_bounds__(256) void k5_node(
    const unsigned int* __restrict__ rpd, const unsigned short* __restrict__ slots16,
    const float2* __restrict__ elsc, const float* __restrict__ er,
    const unsigned char* __restrict__ feat8, const float* __restrict__ bias,
    float* __restrict__ out, int N) {
    const int lane = threadIdx.x & 63;
    const int p = blockIdx.x & 7;
    const int g = blockIdx.x >> 3;
    const int NPER = (N + 7) >> 3;
    const int hi = ((p + 1) * NPER < N) ? (p + 1) * NPER : N;
    const int n = p * NPER + g * 4 + (threadIdx.x >> 6);
    if (n >= hi) return;                 // wave-uniform exit
    const unsigned rd = rpd[n];
    const int deg = (int)(rd & 0xffu);
    const unsigned short* sp = slots16 + (rd >> 8);

    const int sub4 = lane >> 4;     // edge within group of 4
    const int q4 = lane & 15;       // feats 8q4 .. 8q4+7
    const int hh = q4 >> 2;         // head of those feats
    const float ernh = er[n * HEADS + hh];

    float acc[8];
#pragma unroll
    for (int j = 0; j < 8; j++) acc[j] = 0.f;
    float den = 0.f;

#pragma unroll 4
    for (int i = sub4; i < deg; i += 4) {
        int s = (int)sp[i];                       // 16-lane broadcast load
        float2 es = elsc[s * HEADS + hh];         // {el, scale/127}
        float ex = __expf(leaky(es.x + ernh));
        uint2 u = *(const uint2*)(feat8 + (size_t)s * FEAT_ALL + q4 * 8);
        float exs = ex * es.y;
        den += ex;
        union { uint2 v; signed char b[8]; } cv;
        cv.v = u;
        acc[0] += exs * (float)cv.b[0];
        acc[1] += exs * (float)cv.b[1];
        acc[2] += exs * (float)cv.b[2];
        acc[3] += exs * (float)cv.b[3];
        acc[4] += exs * (float)cv.b[4];
        acc[5] += exs * (float)cv.b[5];
        acc[6] += exs * (float)cv.b[6];
        acc[7] += exs * (float)cv.b[7];
    }

    // joint reduction over the 4 edge-subgroups
#pragma unroll
    for (int j = 0; j < 8; j++) {
        acc[j] += __shfl_xor(acc[j], 16);
        acc[j] += __shfl_xor(acc[j], 32);
    }
    den += __shfl_xor(den, 16);
    den += __shfl_xor(den, 32);
    const float idh = 1.f / fmaxf(den, 1e-9f);

    // bias + relu (per head), then mean over heads (lanes q4, q4^4, q4^8, q4^12)
    const float4 b0 = ((const float4*)bias)[q4 * 2];
    const float4 b1 = ((const float4*)bias)[q4 * 2 + 1];
    float v[8];
    v[0] = fmaxf(acc[0] * idh + b0.x, 0.f); v[1] = fmaxf(acc[1] * idh + b0.y, 0.f);
    v[2] = fmaxf(acc[2] * idh + b0.z, 0.f); v[3] = fmaxf(acc[3] * idh + b0.w, 0.f);
    v[4] = fmaxf(acc[4] * idh + b1.x, 0.f); v[5] = fmaxf(acc[5] * idh + b1.y, 0.f);
    v[6] = fmaxf(acc[6] * idh + b1.z, 0.f); v[7] = fmaxf(acc[7] * idh + b1.w, 0.f);
#pragma unroll
    for (int j = 0; j < 8; j++) {
        v[j] += __shfl_xor(v[j], 4);
        v[j] += __shfl_xor(v[j], 8);
    }
    if (lane < 4) {
        float4 o0 = make_float4(v[0] * 0.25f, v[1] * 0.25f, v[2] * 0.25f, v[3] * 0.25f);
        float4 o1 = make_float4(v[4] * 0.25f, v[5] * 0.25f, v[6] * 0.25f, v[7] * 0.25f);
        float* op = out + (size_t)n * FEAT_OUT + lane * 8;
        ((float4*)op)[0] = o0;
        ((float4*)op)[1] = o1;
    }
}

extern "C" void kernel_launch(void* const* d_in, const int* in_sizes, int n_in,
                              void* d_out, int out_size, void* d_ws, size_t ws_size,
                              hipStream_t stream) {
    const float* h      = (const float*)d_in[0];
    const float* W      = (const float*)d_in[1];
    const float* attn_l = (const float*)d_in[2];
    const float* attn_r = (const float*)d_in[3];
    const float* bias   = (const float*)d_in[4];
    const int*   src    = (const int*)d_in[5];
    const int*   dst    = (const int*)d_in[6];
    float* out = (float*)d_out;

    const int N = in_sizes[0] / IN_FEAT;
    const int E = in_sizes[5];
    const int nbkt = (N + 127) >> 7;                       // 391 for N=50000
    const int che = (((E + NBLK1 - 1) / NBLK1) + 3) & ~3;  // chunk edges, x4

    // workspace layout (256B-aligned slabs)
    char* w = (char*)d_ws;
    auto alloc = [&](size_t bytes) { char* r = w; w += (bytes + 255) & ~(size_t)255; return r; };
    unsigned char* feat8   = (unsigned char*)alloc((size_t)N * FEAT_ALL);
    float2*        elsc    = (float2*)alloc((size_t)N * HEADS * sizeof(float2));
    float*         er      = (float*)alloc((size_t)N * HEADS * sizeof(float));
    unsigned int*  rpd     = (unsigned int*)alloc((size_t)N * 4);
    unsigned int*  ds      = (unsigned int*)alloc((size_t)E * 4);
    unsigned int*  srt     = (unsigned int*)alloc((size_t)E * 4);
    unsigned short* slots16 = (unsigned short*)alloc((size_t)E * 2);
    int*           hist    = (int*)alloc((size_t)NBLK1 * nbkt * 4);
    int*           base1   = (int*)alloc((size_t)NBLK1 * nbkt * 4);
    int*           tot     = (int*)alloc((size_t)nbkt * 4);
    int*           bb      = (int*)alloc((size_t)(nbkt + 1) * 4);

    const int nG = (N + 63) / 64;
    k1_fused<<<nG + NBLK1, 256, 0, stream>>>(src, dst, E, che, nbkt, ds, hist,
                                             h, W, attn_l, attn_r,
                                             feat8, elsc, er, N, nG);
    s1_scan<<<nbkt, 256, 0, stream>>>(hist, base1, tot, nbkt);
    s2_scan<<<1, 256, 0, stream>>>(tot, bb, nbkt);
    p2_place<<<NBLK1, 256, 0, stream>>>(ds, base1, bb, srt, E, che, nbkt);
    p3_bucket<<<nbkt, 256, 0, stream>>>(srt, bb, slots16, rpd, N);

    const int NPER = (N + 7) >> 3;
    const int nb5 = 8 * ((NPER + 3) / 4);
    k5_node<<<nb5, 256, 0, stream>>>(rpd, slots16, elsc, er, feat8, bias, out, N);
}